// Round 3
// baseline (1074.552 us; speedup 1.0000x reference)
//
#include <hip/hip_runtime.h>

#define DEVI __device__ __forceinline__

typedef unsigned short u16;
typedef unsigned int u32;
typedef __bf16 bf16x8 __attribute__((ext_vector_type(8)));
typedef u16 u16x8 __attribute__((ext_vector_type(8)));
typedef float f32x4 __attribute__((ext_vector_type(4)));

static constexpr int VOCAB = 50257;
static constexpr int HDIM = 1024;
static constexpr int BATCH = 512;
static constexpr int G4 = 4096;
static constexpr int NSTRIP = (VOCAB + 63) / 64;  // 786 strips of 64 cols
static constexpr int LPB = 50264;                 // padded bf16 logits row stride (16B-aligned rows)

DEVI u16 f2bf(float f) {
  u32 u = __float_as_uint(f);
  return (u16)((u + 0x7FFFu + ((u >> 16) & 1u)) >> 16);
}
DEVI float bf2f(u16 s) { return __uint_as_float(((u32)s) << 16); }
// XOR swizzle for [row][64 bf16] = 128B rows (G4: breaks 16/32-way bank conflict)
DEVI int swz(int row, int kbyte) { return row * 128 + (kbyte ^ ((row & 7) << 4)); }

// ---------------- prep: emb gather + bf16 casts ----------------
__global__ __launch_bounds__(256) void prep_kernel(
    const int* __restrict__ x, const float* __restrict__ emb,
    const float* __restrict__ h0, const float* __restrict__ h1,
    u16* __restrict__ a0b, u16* __restrict__ h0b, u16* __restrict__ h1b) {
  int i = blockIdx.x * 256 + threadIdx.x;
  if (i >= BATCH * HDIM) return;
  int b = i >> 10, j = i & (HDIM - 1);
  a0b[i] = f2bf(emb[(long)x[b] * HDIM + j]);
  h0b[i] = f2bf(h0[i]);
  h1b[i] = f2bf(h1[i]);
}

// ---------------- GEMM: C = A1@B1 (+ A2@B2), A bf16 [512][K], B f32 [K][N] cast on the fly
// MODE 0: gates epilogue (+bias1+bias2 -> f32 out)
// MODE 1: FC epilogue (+bias1, bf16 logits store, per-64col-strip softmax partials)
template <int BM, int BN, int WR, int WC, int MODE>
__global__ __launch_bounds__(WR * WC * 64) void gemm_kernel(
    const u16* __restrict__ A1, const float* __restrict__ B1,
    const u16* __restrict__ A2, const float* __restrict__ B2,
    const float* __restrict__ bias1, const float* __restrict__ bias2,
    float* __restrict__ gatesOut, u16* __restrict__ logitsOut,
    float2* __restrict__ partials, int N, int K) {
  constexpr int THREADS = WR * WC * 64;
  constexpr int WM = BM / WR, WN = BN / WC;
  constexpr int MI = WM / 16, NI = WN / 16;

  const int mtiles = BATCH / BM;
  int bid = blockIdx.x;
  int m0 = (bid % mtiles) * BM;   // m fastest: M-tiles sharing B cols dispatch adjacently (L3 reuse)
  int n0 = (bid / mtiles) * BN;
  int tid = threadIdx.x;
  int lane = tid & 63;
  int wv = tid >> 6;
  int wm = wv / WC, wn = wv % WC;
  int lr = lane & 15, lg = lane >> 4;

  __shared__ alignas(16) char a_smem[BM * 128];
  __shared__ alignas(16) char b_smem[BN * 128];

  f32x4 acc[MI][NI];
#pragma unroll
  for (int mi = 0; mi < MI; ++mi)
#pragma unroll
    for (int ni = 0; ni < NI; ++ni) acc[mi][ni] = 0.f;

  const int npairs = (A2 != nullptr) ? 2 : 1;
  for (int pr = 0; pr < npairs; ++pr) {
    const u16* Ag = pr ? A2 : A1;
    const float* Bg = pr ? B2 : B1;
    for (int kt = 0; kt < K; kt += 64) {
      __syncthreads();
      // stage A tile: BM x 64 bf16, 16B chunks, swizzled
      for (int c = tid; c < BM * 8; c += THREADS) {
        int row = c >> 3, kc = c & 7;
        u16x8 v = *reinterpret_cast<const u16x8*>(Ag + (long)(m0 + row) * K + kt + kc * 8);
        *reinterpret_cast<u16x8*>(a_smem + swz(row, kc * 16)) = v;
      }
      // stage B tile: 64 x BN f32 -> bf16, transposed to [n][k] (coalesced col reads per k-row)
      for (int slot = tid; slot < BN * 8; slot += THREADS) {
        int n_local = slot % BN;
        int kg = (slot / BN) * 8;
        int n = n0 + n_local;
        u16x8 w;
#pragma unroll
        for (int j = 0; j < 8; ++j) {
          float v = 0.f;
          if (MODE == 0 || n < N) v = Bg[(long)(kt + kg + j) * N + n];
          w[j] = f2bf(v);
        }
        *reinterpret_cast<u16x8*>(b_smem + swz(n_local, kg * 2)) = w;
      }
      __syncthreads();
#pragma unroll
      for (int kk = 0; kk < 2; ++kk) {
        int kb = kk * 64 + lg * 16;
        bf16x8 af[MI], bfr[NI];
#pragma unroll
        for (int mi = 0; mi < MI; ++mi)
          af[mi] = *reinterpret_cast<const bf16x8*>(a_smem + swz(wm * WM + mi * 16 + lr, kb));
#pragma unroll
        for (int ni = 0; ni < NI; ++ni)
          bfr[ni] = *reinterpret_cast<const bf16x8*>(b_smem + swz(wn * WN + ni * 16 + lr, kb));
#pragma unroll
        for (int mi = 0; mi < MI; ++mi)
#pragma unroll
          for (int ni = 0; ni < NI; ++ni)
            acc[mi][ni] =
                __builtin_amdgcn_mfma_f32_16x16x32_bf16(af[mi], bfr[ni], acc[mi][ni], 0, 0, 0);
      }
    }
  }

  if (MODE == 0) {
#pragma unroll
    for (int mi = 0; mi < MI; ++mi)
#pragma unroll
      for (int ni = 0; ni < NI; ++ni)
#pragma unroll
        for (int r = 0; r < 4; ++r) {
          int row = m0 + wm * WM + mi * 16 + lg * 4 + r;
          int col = n0 + wn * WN + ni * 16 + lr;
          gatesOut[(long)row * N + col] = acc[mi][ni][r] + bias1[col] + bias2[col];
        }
  } else {
#pragma unroll
    for (int mi = 0; mi < MI; ++mi) {
#pragma unroll
      for (int r = 0; r < 4; ++r) {
        int row = m0 + wm * WM + mi * 16 + lg * 4 + r;
        float vals[NI];
        float vmax = -3.0e38f;
#pragma unroll
        for (int ni = 0; ni < NI; ++ni) {
          int col = n0 + wn * WN + ni * 16 + lr;
          float v = acc[mi][ni][r];
          if (col < N) {
            v += bias1[col];
            vmax = fmaxf(vmax, v);
          }
          vals[ni] = v;
        }
#pragma unroll
        for (int off = 1; off < 16; off <<= 1) vmax = fmaxf(vmax, __shfl_xor(vmax, off, 64));
        float ssum = 0.f;
#pragma unroll
        for (int ni = 0; ni < NI; ++ni) {
          int col = n0 + wn * WN + ni * 16 + lr;
          if (col < N) ssum += __expf(vals[ni] - vmax);
        }
#pragma unroll
        for (int off = 1; off < 16; off <<= 1) ssum += __shfl_xor(ssum, off, 64);
        int sbase = n0 + wn * WN;
        if (lr == 0 && sbase < N)
          partials[(long)row * NSTRIP + (sbase >> 6)] = make_float2(vmax, ssum);
        // bf16 logits store, pair-packed to u32 via lane exchange
#pragma unroll
        for (int ni = 0; ni < NI; ++ni) {
          int col = n0 + wn * WN + ni * 16 + lr;
          float v = vals[ni];
          float vn = __shfl_xor(v, 1, 64);
          if (!(lane & 1)) {
            if (col + 1 < N) {
              u32 pk = (u32)f2bf(v) | ((u32)f2bf(vn) << 16);
              *reinterpret_cast<u32*>(logitsOut + (long)row * LPB + col) = pk;
            } else if (col < N) {
              logitsOut[(long)row * LPB + col] = f2bf(v);
            }
          }
        }
      }
    }
  }
}

// ---------------- LSTM cell elementwise ----------------
__global__ __launch_bounds__(256) void cell_kernel(
    const float* __restrict__ gates, const float* __restrict__ c_in,
    float* __restrict__ nc_out, float* __restrict__ nh_out, u16* __restrict__ nh_b) {
  int i = blockIdx.x * 256 + threadIdx.x;
  if (i >= BATCH * HDIM) return;
  int b = i >> 10, j = i & (HDIM - 1);
  const float* g = gates + (long)b * G4;
  float ig = 1.f / (1.f + __expf(-g[j]));
  float fg = 1.f / (1.f + __expf(-g[HDIM + j]));
  float og = 1.f / (1.f + __expf(-g[2 * HDIM + j]));
  float gg = tanhf(g[3 * HDIM + j]);
  float nc = fg * c_in[i] + ig * gg;
  float nh = og * tanhf(nc);
  nc_out[i] = nc;
  nh_out[i] = nh;
  nh_b[i] = f2bf(nh);
}

// ---------------- combine softmax partials per row ----------------
__global__ __launch_bounds__(256) void reduce_kernel(const float2* __restrict__ partials,
                                                     float* __restrict__ rowoff) {
  int row = blockIdx.x;
  int tid = threadIdx.x;
  const float2* p = partials + (long)row * NSTRIP;
  float2 loc[4];
  int cnt = 0;
  float m = -3.0e38f;
  for (int s = tid; s < NSTRIP; s += 256) {
    float2 v = p[s];
    loc[cnt++] = v;
    m = fmaxf(m, v.x);
  }
#pragma unroll
  for (int off = 1; off < 64; off <<= 1) m = fmaxf(m, __shfl_xor(m, off, 64));
  __shared__ float sm[4], ss[4];
  if ((tid & 63) == 0) sm[tid >> 6] = m;
  __syncthreads();
  float M = fmaxf(fmaxf(sm[0], sm[1]), fmaxf(sm[2], sm[3]));
  float s = 0.f;
  for (int i = 0; i < cnt; ++i) s += loc[i].y * __expf(loc[i].x - M);
#pragma unroll
  for (int off = 1; off < 64; off <<= 1) s += __shfl_xor(s, off, 64);
  if ((tid & 63) == 0) ss[tid >> 6] = s;
  __syncthreads();
  if (tid == 0) rowoff[row] = M + logf(ss[0] + ss[1] + ss[2] + ss[3]);
}

// ---------------- finalize: logp = logits - rowoff ----------------
__global__ __launch_bounds__(256) void finalize_kernel(const u16* __restrict__ logits,
                                                       const float* __restrict__ rowoff,
                                                       float* __restrict__ outp) {
  const int total = BATCH * VOCAB;
  for (int i = blockIdx.x * 256 + threadIdx.x; i < total; i += 2048 * 256) {
    int row = i / VOCAB;
    int col = i - row * VOCAB;
    outp[i] = bf2f(logits[(long)row * LPB + col]) - rowoff[row];
  }
}

extern "C" void kernel_launch(void* const* d_in, const int* in_sizes, int n_in,
                              void* d_out, int out_size, void* d_ws, size_t ws_size,
                              hipStream_t stream) {
  const int* x = (const int*)d_in[0];
  const float* c0 = (const float*)d_in[1];
  const float* h0 = (const float*)d_in[2];
  const float* c1 = (const float*)d_in[3];
  const float* h1 = (const float*)d_in[4];
  const float* emb = (const float*)d_in[5];
  const float* W = (const float*)d_in[6];
  const float* Wb = (const float*)d_in[7];
  const float* U = (const float*)d_in[8];
  const float* Ub = (const float*)d_in[9];
  const float* fcW = (const float*)d_in[10];
  const float* fcb = (const float*)d_in[11];
  float* outp = (float*)d_out;

  char* ws = (char*)d_ws;
  const size_t MB = (size_t)1 << 20;
  u16* a0b = (u16*)(ws + 0 * MB);        // 1 MB
  u16* h0b = (u16*)(ws + 1 * MB);        // 1 MB
  u16* h1b = (u16*)(ws + 2 * MB);        // 1 MB
  u16* nh0b = (u16*)(ws + 3 * MB);       // 1 MB
  u16* nh1b = (u16*)(ws + 4 * MB);       // 1 MB
  float* gates = (float*)(ws + 5 * MB);  // 8 MB
  float2* partials = (float2*)(ws + 13 * MB);  // 3.1 MB
  float* rowoff = (float*)(ws + 17 * MB);      // 2 KB
  u16* logits = (u16*)(ws + 18 * MB);          // 49.1 MB  (total ~67.2 MB)

  float* logp = outp;
  float* nc0 = outp + (size_t)BATCH * VOCAB;
  float* nh0 = nc0 + BATCH * HDIM;
  float* nc1 = nh0 + BATCH * HDIM;
  float* nh1 = nc1 + BATCH * HDIM;

  prep_kernel<<<BATCH * HDIM / 256, 256, 0, stream>>>(x, emb, h0, h1, a0b, h0b, h1b);
  gemm_kernel<64, 128, 2, 2, 0><<<(BATCH / 64) * (G4 / 128), 256, 0, stream>>>(
      a0b, W, h0b, U, Wb, Ub, gates, nullptr, nullptr, G4, HDIM);
  cell_kernel<<<BATCH * HDIM / 256, 256, 0, stream>>>(gates, c0, nc0, nh0, nh0b);
  gemm_kernel<64, 128, 2, 2, 0><<<(BATCH / 64) * (G4 / 128), 256, 0, stream>>>(
      nh0b, W + (size_t)HDIM * G4, h1b, U + (size_t)HDIM * G4, Wb + G4, Ub + G4,
      gates, nullptr, nullptr, G4, HDIM);
  cell_kernel<<<BATCH * HDIM / 256, 256, 0, stream>>>(gates, c1, nc1, nh1, nh1b);
  gemm_kernel<128, 128, 2, 2, 1><<<(BATCH / 128) * ((VOCAB + 127) / 128), 256, 0, stream>>>(
      nh1b, fcW, nullptr, nullptr, fcb, nullptr, nullptr, logits, partials, VOCAB, HDIM);
  reduce_kernel<<<BATCH, 256, 0, stream>>>(partials, rowoff);
  finalize_kernel<<<2048, 256, 0, stream>>>(logits, rowoff, logp);
}

// Round 4
// 659.391 us; speedup vs baseline: 1.6296x; 1.6296x over previous
//
#include <hip/hip_runtime.h>

#define DEVI __device__ __forceinline__

typedef unsigned short u16;
typedef unsigned int u32;
typedef __bf16 bf16x8 __attribute__((ext_vector_type(8)));
typedef u16 u16x8 __attribute__((ext_vector_type(8)));
typedef u16 u16x4 __attribute__((ext_vector_type(4)));
typedef float f32x4 __attribute__((ext_vector_type(4)));

static constexpr int VOCAB = 50257;
static constexpr int HDIM = 1024;
static constexpr int BATCH = 512;
static constexpr int G4 = 4096;
static constexpr int NSTRIP = (VOCAB + 63) / 64;  // 786
static constexpr int LPB = 50264;                 // padded bf16 logits row stride

DEVI u16 f2bf(float f) {
  u32 u = __float_as_uint(f);
  return (u16)((u + 0x7FFFu + ((u >> 16) & 1u)) >> 16);
}
DEVI float bf2f(u16 s) { return __uint_as_float(((u32)s) << 16); }
// XOR swizzle for rows of 128 bytes (64 bf16): breaks stride-128 bank conflicts
DEVI int swz(int row, int kbyte) { return row * 128 + (kbyte ^ ((row & 7) << 4)); }
DEVI void gload_lds16(const void* g, void* l) {
  __builtin_amdgcn_global_load_lds((const __attribute__((address_space(1))) unsigned int*)g,
                                   (__attribute__((address_space(3))) unsigned int*)l, 16, 0, 0);
}
#define SCHED_FENCE() __builtin_amdgcn_sched_barrier(0)

// ---------------- prep: emb gather + bf16 casts ----------------
__global__ __launch_bounds__(256) void prep_kernel(
    const int* __restrict__ x, const float* __restrict__ emb,
    const float* __restrict__ h0, const float* __restrict__ h1,
    u16* __restrict__ a0b, u16* __restrict__ h0b, u16* __restrict__ h1b) {
  int i = blockIdx.x * 256 + threadIdx.x;
  if (i >= BATCH * HDIM) return;
  int b = i >> 10, j = i & (HDIM - 1);
  a0b[i] = f2bf(emb[(long)x[b] * HDIM + j]);
  h0b[i] = f2bf(h0[i]);
  h1b[i] = f2bf(h1[i]);
}

// ---------------- GEMM v2: full-M (512) x BN strip per block, 8 waves, K=1024.
// A bf16 [512][1024] staged to LDS via global_load_lds (source-swizzled).
// B f32 [1024][N] reg-staged -> bf16 -> double-buffered LDS; counted vmcnt keeps
// next B tile in flight across barriers (T3/T4 2-phase pipeline).
// MODE 0: partial gates (+bias) per pair (blockIdx.y); MODE 1: FC + softmax partials.
template <int BN, int MODE>
__global__ __launch_bounds__(512, 4) void gemm2_kernel(
    const u16* __restrict__ Ax, const u16* __restrict__ Ah,
    const float* __restrict__ Bx, const float* __restrict__ Bh,
    const float* __restrict__ biasX, const float* __restrict__ biasH,
    float* __restrict__ outX, float* __restrict__ outH,
    u16* __restrict__ logitsOut, float2* __restrict__ partials, int N) {
  constexpr int NI = BN / 16;            // 4 (FC) or 2 (gates)
  constexpr int NK = HDIM / 64;          // 16 k-steps
  constexpr int BL = (BN * 64) / 512;    // f32 per thread per B tile: 8 or 4

  const int pair = (MODE == 0) ? blockIdx.y : 0;
  const u16* A = pair ? Ah : Ax;
  const float* B = pair ? Bh : Bx;
  const float* bias = pair ? biasH : biasX;
  float* outG = pair ? outH : outX;
  const int n0 = blockIdx.x * BN;

  const int tid = threadIdx.x;
  const int lane = tid & 63, wv = tid >> 6;
  const int lr = lane & 15, lg = lane >> 4;

  __shared__ alignas(16) char a_smem[512 * 128];
  __shared__ alignas(16) char b_smem[2][BN * 128];

  f32x4 acc[4][NI];
#pragma unroll
  for (int mi = 0; mi < 4; ++mi)
#pragma unroll
    for (int ni = 0; ni < NI; ++ni) acc[mi][ni] = 0.f;

  // B staging geometry
  const int n_local = tid & (BN - 1);
  const int kgrp = tid / BN;  // 0..7 (BN=64) / 0..15 (BN=32)
  const bool nValid = (MODE == 0) || (n0 + n_local < N);
  int nB = n0 + n_local;
  if (MODE == 1 && nB >= N) nB = N - 1;  // clamp: always issue BL loads (vmcnt discipline)

  // A staging geometry: wave stages rows [wv*64, wv*64+64). Issue i fills LDS 16B-slots
  // [wv*512 + i*64 + lane]; row_local = i*8 + (lane>>3), kc = lane&7.
  // Source chunk pre-swizzled: g = kc ^ (row_local & 7) = (lane&7) ^ (lane>>3).
  const int a_g = (lane & 7) ^ (lane >> 3);
  const u16* Arow = A + (size_t)(wv * 64 + (lane >> 3)) * HDIM + a_g * 8;
  char* a_lbase = a_smem + wv * 8192;

  float bstage[BL];
#define LOADB(t)                                                             \
  {                                                                          \
    size_t base_ = ((size_t)(t) * 64 + kgrp * BL) * N + nB;                  \
    _Pragma("unroll") for (int j = 0; j < BL; ++j)                           \
        bstage[j] = B[base_ + (size_t)j * N];                                \
  }
#define WRITEB(bufi)                                                         \
  {                                                                          \
    if constexpr (BN == 64) {                                                \
      u16x8 w;                                                               \
      _Pragma("unroll") for (int j = 0; j < 8; ++j)                          \
          w[j] = f2bf(nValid ? bstage[j] : 0.f);                             \
      *reinterpret_cast<u16x8*>(b_smem[bufi] + swz(n_local, kgrp * 16)) = w; \
    } else {                                                                 \
      u16x4 w;                                                               \
      _Pragma("unroll") for (int j = 0; j < 4; ++j)                          \
          w[j] = f2bf(nValid ? bstage[j] : 0.f);                             \
      *reinterpret_cast<u16x4*>(b_smem[bufi] + swz(n_local, kgrp * 8)) = w;  \
    }                                                                        \
  }

  // prologue: B tile 0
  LOADB(0);
  WRITEB(0);
  asm volatile("s_waitcnt lgkmcnt(0)" ::: "memory");
  SCHED_FENCE();

  int buf = 0;
  for (int t = 0; t < NK; ++t) {
    __builtin_amdgcn_s_barrier();  // A_lds / B[buf] ready for consumption; prev reads done
    SCHED_FENCE();
    // stage A slice t (8 x global_load_lds, 16B each)
#pragma unroll
    for (int i = 0; i < 8; ++i)
      gload_lds16(Arow + (size_t)i * 8 * HDIM + t * 64, a_lbase + i * 1024);
    SCHED_FENCE();
    const bool hasNext = (t + 1 < NK);
    if (hasNext) {
      LOADB(t + 1);  // stays in flight across the barrier (counted vmcnt)
      if constexpr (BN == 64) asm volatile("s_waitcnt vmcnt(8)" ::: "memory");
      else asm volatile("s_waitcnt vmcnt(4)" ::: "memory");
    } else {
      asm volatile("s_waitcnt vmcnt(0)" ::: "memory");
    }
    SCHED_FENCE();
    __builtin_amdgcn_s_barrier();  // all waves' A landed
    SCHED_FENCE();
#pragma unroll
    for (int kk = 0; kk < 2; ++kk) {
      const int kb = kk * 64 + lg * 16;
      bf16x8 bfr[NI];
#pragma unroll
      for (int ni = 0; ni < NI; ++ni)
        bfr[ni] = *reinterpret_cast<const bf16x8*>(b_smem[buf] + swz(ni * 16 + lr, kb));
#pragma unroll
      for (int mi = 0; mi < 4; ++mi) {
        bf16x8 af =
            *reinterpret_cast<const bf16x8*>(a_smem + swz(wv * 64 + mi * 16 + lr, kb));
#pragma unroll
        for (int ni = 0; ni < NI; ++ni)
          acc[mi][ni] =
              __builtin_amdgcn_mfma_f32_16x16x32_bf16(af, bfr[ni], acc[mi][ni], 0, 0, 0);
      }
    }
    if (hasNext) {
      WRITEB(buf ^ 1);  // compiler inserts vmcnt wait for bstage deps
      asm volatile("s_waitcnt lgkmcnt(0)" ::: "memory");
      SCHED_FENCE();
      buf ^= 1;
    }
  }

  // ---------------- epilogues ----------------
  if constexpr (MODE == 0) {
#pragma unroll
    for (int mi = 0; mi < 4; ++mi)
#pragma unroll
      for (int ni = 0; ni < NI; ++ni)
#pragma unroll
        for (int r = 0; r < 4; ++r) {
          int row = wv * 64 + mi * 16 + lg * 4 + r;
          int col = n0 + ni * 16 + lr;
          outG[(size_t)row * G4 + col] = acc[mi][ni][r] + bias[col];
        }
  } else {
#pragma unroll
    for (int mi = 0; mi < 4; ++mi) {
#pragma unroll
      for (int r = 0; r < 4; ++r) {
        int row = wv * 64 + mi * 16 + lg * 4 + r;
        float vals[NI];
        float vmax = -3.0e38f;
#pragma unroll
        for (int ni = 0; ni < NI; ++ni) {
          int col = n0 + ni * 16 + lr;
          float v = acc[mi][ni][r];
          if (col < N) {
            v += bias[col];
            vmax = fmaxf(vmax, v);
          }
          vals[ni] = v;
        }
#pragma unroll
        for (int off = 1; off < 16; off <<= 1) vmax = fmaxf(vmax, __shfl_xor(vmax, off, 64));
        float ssum = 0.f;
#pragma unroll
        for (int ni = 0; ni < NI; ++ni) {
          int col = n0 + ni * 16 + lr;
          if (col < N) ssum += __expf(vals[ni] - vmax);
        }
#pragma unroll
        for (int off = 1; off < 16; off <<= 1) ssum += __shfl_xor(ssum, off, 64);
        if (lr == 0) partials[(size_t)row * NSTRIP + (n0 >> 6)] = make_float2(vmax, ssum);
#pragma unroll
        for (int ni = 0; ni < NI; ++ni) {
          int col = n0 + ni * 16 + lr;
          float v = vals[ni];
          float vn = __shfl_xor(v, 1, 64);
          if (!(lane & 1)) {
            if (col + 1 < N) {
              u32 pk = (u32)f2bf(v) | ((u32)f2bf(vn) << 16);
              *reinterpret_cast<u32*>(logitsOut + (size_t)row * LPB + col) = pk;
            } else if (col < N) {
              logitsOut[(size_t)row * LPB + col] = f2bf(v);
            }
          }
        }
      }
    }
  }
#undef LOADB
#undef WRITEB
}

// ---------------- LSTM cell elementwise (sums the two gate partials) ----------------
__global__ __launch_bounds__(256) void cell_kernel(
    const float* __restrict__ gX, const float* __restrict__ gH,
    const float* __restrict__ c_in, float* __restrict__ nc_out,
    float* __restrict__ nh_out, u16* __restrict__ nh_b) {
  int i = blockIdx.x * 256 + threadIdx.x;
  if (i >= BATCH * HDIM) return;
  int b = i >> 10, j = i & (HDIM - 1);
  const float* px = gX + (size_t)b * G4;
  const float* ph = gH + (size_t)b * G4;
  float gi = px[j] + ph[j];
  float gf = px[HDIM + j] + ph[HDIM + j];
  float go = px[2 * HDIM + j] + ph[2 * HDIM + j];
  float gg = px[3 * HDIM + j] + ph[3 * HDIM + j];
  float ig = 1.f / (1.f + __expf(-gi));
  float fg = 1.f / (1.f + __expf(-gf));
  float og = 1.f / (1.f + __expf(-go));
  float g = tanhf(gg);
  float nc = fg * c_in[i] + ig * g;
  float nh = og * tanhf(nc);
  nc_out[i] = nc;
  nh_out[i] = nh;
  nh_b[i] = f2bf(nh);
}

// ---------------- combine softmax partials per row ----------------
__global__ __launch_bounds__(256) void reduce_kernel(const float2* __restrict__ partials,
                                                     float* __restrict__ rowoff) {
  int row = blockIdx.x;
  int tid = threadIdx.x;
  const float2* p = partials + (size_t)row * NSTRIP;
  float2 loc[4];
  int cnt = 0;
  float m = -3.0e38f;
  for (int s = tid; s < NSTRIP; s += 256) {
    float2 v = p[s];
    loc[cnt++] = v;
    m = fmaxf(m, v.x);
  }
#pragma unroll
  for (int off = 1; off < 64; off <<= 1) m = fmaxf(m, __shfl_xor(m, off, 64));
  __shared__ float sm[4], ss[4];
  if ((tid & 63) == 0) sm[tid >> 6] = m;
  __syncthreads();
  float M = fmaxf(fmaxf(sm[0], sm[1]), fmaxf(sm[2], sm[3]));
  float s = 0.f;
  for (int i = 0; i < cnt; ++i) s += loc[i].y * __expf(loc[i].x - M);
#pragma unroll
  for (int off = 1; off < 64; off <<= 1) s += __shfl_xor(s, off, 64);
  if ((tid & 63) == 0) ss[tid >> 6] = s;
  __syncthreads();
  if (tid == 0) rowoff[row] = M + logf(ss[0] + ss[1] + ss[2] + ss[3]);
}

// ---------------- finalize: logp = logits - rowoff ----------------
__global__ __launch_bounds__(256) void finalize_kernel(const u16* __restrict__ logits,
                                                       const float* __restrict__ rowoff,
                                                       float* __restrict__ outp) {
  const int total = BATCH * VOCAB;
  for (int i = blockIdx.x * 256 + threadIdx.x; i < total; i += 2048 * 256) {
    int row = i / VOCAB;
    int col = i - row * VOCAB;
    outp[i] = bf2f(logits[(size_t)row * LPB + col]) - rowoff[row];
  }
}

extern "C" void kernel_launch(void* const* d_in, const int* in_sizes, int n_in,
                              void* d_out, int out_size, void* d_ws, size_t ws_size,
                              hipStream_t stream) {
  const int* x = (const int*)d_in[0];
  const float* c0 = (const float*)d_in[1];
  const float* h0 = (const float*)d_in[2];
  const float* c1 = (const float*)d_in[3];
  const float* h1 = (const float*)d_in[4];
  const float* emb = (const float*)d_in[5];
  const float* W = (const float*)d_in[6];
  const float* Wb = (const float*)d_in[7];
  const float* U = (const float*)d_in[8];
  const float* Ub = (const float*)d_in[9];
  const float* fcW = (const float*)d_in[10];
  const float* fcb = (const float*)d_in[11];
  float* outp = (float*)d_out;

  char* ws = (char*)d_ws;
  const size_t MB = (size_t)1 << 20;
  u16* a0b = (u16*)(ws + 0 * MB);
  u16* h0b = (u16*)(ws + 1 * MB);
  u16* h1b = (u16*)(ws + 2 * MB);
  u16* nh0b = (u16*)(ws + 3 * MB);
  u16* nh1b = (u16*)(ws + 4 * MB);
  float* gX = (float*)(ws + 5 * MB);            // 8 MB
  float* gH = (float*)(ws + 13 * MB);           // 8 MB
  float2* partials = (float2*)(ws + 21 * MB);   // 3.2 MB
  float* rowoff = (float*)(ws + 25 * MB);       // 2 KB
  u16* logits = (u16*)(ws + 26 * MB);           // 51.5 MB (total ~77.5 MB)

  float* logp = outp;
  float* nc0 = outp + (size_t)BATCH * VOCAB;
  float* nh0 = nc0 + BATCH * HDIM;
  float* nc1 = nh0 + BATCH * HDIM;
  float* nh1 = nc1 + BATCH * HDIM;

  prep_kernel<<<BATCH * HDIM / 256, 256, 0, stream>>>(x, emb, h0, h1, a0b, h0b, h1b);
  gemm2_kernel<32, 0><<<dim3(G4 / 32, 2), 512, 0, stream>>>(
      a0b, h0b, W, U, Wb, Ub, gX, gH, nullptr, nullptr, G4);
  cell_kernel<<<BATCH * HDIM / 256, 256, 0, stream>>>(gX, gH, c0, nc0, nh0, nh0b);
  gemm2_kernel<32, 0><<<dim3(G4 / 32, 2), 512, 0, stream>>>(
      nh0b, h1b, W + (size_t)HDIM * G4, U + (size_t)HDIM * G4, Wb + G4, Ub + G4,
      gX, gH, nullptr, nullptr, G4);
  cell_kernel<<<BATCH * HDIM / 256, 256, 0, stream>>>(gX, gH, c1, nc1, nh1, nh1b);
  gemm2_kernel<64, 1><<<(VOCAB + 63) / 64, 512, 0, stream>>>(
      nh1b, nullptr, fcW, nullptr, fcb, nullptr, nullptr, nullptr, logits, partials, VOCAB);
  reduce_kernel<<<BATCH, 256, 0, stream>>>(partials, rowoff);
  finalize_kernel<<<2048, 256, 0, stream>>>(logits, rowoff, logp);
}